// Round 2
// baseline (372.246 us; speedup 1.0000x reference)
//
#include <hip/hip_runtime.h>

#define IN_CH 128
#define OUT_CH 64

// -------- Kernel 1: x = z @ W  ([N,128] @ [128,64] -> [N,64]) --------
// W (32 KB) staged in LDS once per block; grid-stride over rows; one wave
// computes one row (lane = output column), z row loaded as float4.
__global__ void gemm_zw(const float* __restrict__ z, const float* __restrict__ W,
                        float* __restrict__ x, int N) {
    __shared__ float Ws[IN_CH * OUT_CH];
    for (int i = threadIdx.x; i < IN_CH * OUT_CH; i += blockDim.x) Ws[i] = W[i];
    __syncthreads();

    const int rowsPerBlk = blockDim.x >> 6;     // waves per block
    const int col  = threadIdx.x & 63;
    const int warp = threadIdx.x >> 6;

    for (int row = blockIdx.x * rowsPerBlk + warp; row < N;
         row += gridDim.x * rowsPerBlk) {
        const float4* zr = (const float4*)(z + (size_t)row * IN_CH);
        float acc = 0.f;
#pragma unroll
        for (int k4 = 0; k4 < IN_CH / 4; ++k4) {
            float4 v = zr[k4];
            acc = fmaf(v.x, Ws[(k4 * 4 + 0) * OUT_CH + col], acc);
            acc = fmaf(v.y, Ws[(k4 * 4 + 1) * OUT_CH + col], acc);
            acc = fmaf(v.z, Ws[(k4 * 4 + 2) * OUT_CH + col], acc);
            acc = fmaf(v.w, Ws[(k4 * 4 + 3) * OUT_CH + col], acc);
        }
        x[(size_t)row * OUT_CH + col] = acc;
    }
}

// -------- Kernel 2: deg = 1.0 (self-loop) --------
__global__ void deg_init(float* __restrict__ deg, int N) {
    int i = blockIdx.x * blockDim.x + threadIdx.x;
    if (i < N) deg[i] = 1.0f;
}

// -------- Kernel 3: deg[dst] += 1 per edge (edge_index is int32!) --------
__global__ void deg_count(const int* __restrict__ dst,
                          float* __restrict__ deg, int E) {
    int i = blockIdx.x * blockDim.x + threadIdx.x;
    if (i < E) atomicAdd(&deg[dst[i]], 1.0f);
}

// -------- Kernel 4: dinv = rsqrt(deg); y = x*dinv (in place); out seed = y (self-loop) --------
__global__ void scale_y(float* __restrict__ x, const float* __restrict__ deg,
                        float* __restrict__ dinv, float* __restrict__ out, int N) {
    int t = blockIdx.x * blockDim.x + threadIdx.x;
    int row = t >> 6, c = t & 63;
    if (row >= N) return;
    float d = rsqrtf(deg[row]);   // deg >= 1 always (self-loop)
    if (c == 0) dinv[row] = d;
    float y = x[t] * d;
    x[t] = y;                     // y overwrites x in ws
    out[t] = y;                   // self-loop seed (final scale by dinv[dst] later)
}

// -------- Kernel 5: edge scatter. One wave per edge, lane = channel. --------
// out[dst][c] += y[src][c]   (normalization already folded into y and the epilogue)
__global__ void scatter_edges(const int* __restrict__ ei,
                              const float* __restrict__ y,
                              float* __restrict__ out, int E) {
    int e = blockIdx.x * (blockDim.x >> 6) + (threadIdx.x >> 6);
    if (e >= E) return;
    int lane = threadIdx.x & 63;
    int src = ei[e];             // row 0 of [2,E]
    int dst = ei[E + e];         // row 1 of [2,E]
    float v = y[(size_t)src * OUT_CH + lane];
    atomicAdd(&out[(size_t)dst * OUT_CH + lane], v);
}

// -------- Kernel 6: out = relu(out * dinv[row] + b) in place --------
__global__ void relu_bias(float* __restrict__ out, const float* __restrict__ dinv,
                          const float* __restrict__ b, int total) {
    int i = blockIdx.x * blockDim.x + threadIdx.x;
    if (i < total) {
        int row = i >> 6;
        out[i] = fmaxf(fmaf(out[i], dinv[row], b[i & 63]), 0.f);
    }
}

extern "C" void kernel_launch(void* const* d_in, const int* in_sizes, int n_in,
                              void* d_out, int out_size, void* d_ws, size_t ws_size,
                              hipStream_t stream) {
    const float* z  = (const float*)d_in[0];
    const int*   ei = (const int*)d_in[1];     // int32 [2, E]
    const float* W  = (const float*)d_in[2];
    const float* b  = (const float*)d_in[3];
    float*       out = (float*)d_out;

    const int N = in_sizes[0] / IN_CH;   // 50000
    const int E = in_sizes[1] / 2;       // 800000

    // workspace layout: y [N*64 f32] | deg [N f32] | dinv [N f32]  (~13.2 MB)
    float* y    = (float*)d_ws;
    float* deg  = y + (size_t)N * OUT_CH;
    float* dinv = deg + N;

    // 1. x = z @ W  (into y-buffer; scaled in place later)
    gemm_zw<<<512, 256, 0, stream>>>(z, W, y, N);

    // 2-3. degree (dst-based, incl. self-loop)
    deg_init<<<(N + 255) / 256, 256, 0, stream>>>(deg, N);
    deg_count<<<(E + 255) / 256, 256, 0, stream>>>(ei + E, deg, E);

    // 4. y = x*dinv; out seeded with self-loop term
    int totalNC = N * OUT_CH;
    scale_y<<<(totalNC + 255) / 256, 256, 0, stream>>>(y, deg, dinv, out, N);

    // 5. edge messages (atomic scatter-add)
    scatter_edges<<<(E + 3) / 4, 256, 0, stream>>>(ei, y, out, E);

    // 6. epilogue: scale by dinv[dst], bias, relu
    relu_bias<<<(totalNC + 255) / 256, 256, 0, stream>>>(out, dinv, b, totalNC);
}

// Round 3
// 268.134 us; speedup vs baseline: 1.3883x; 1.3883x over previous
//
#include <hip/hip_runtime.h>

#define IN_CH 128
#define OUT_CH 64

// ---- Kernel: histogram of dst (int32 atomics) ----
__global__ void hist_dst(const int* __restrict__ dst, int* __restrict__ count, int E) {
    int i = blockIdx.x * blockDim.x + threadIdx.x;
    if (i < E) atomicAdd(&count[dst[i]], 1);
}

// ---- Scan A: per-1024-chunk partial sums ----
__global__ void scan_a(const int* __restrict__ count, int* __restrict__ bsum, int N) {
    __shared__ int tsum[256];
    int base = blockIdx.x * 1024 + threadIdx.x * 4;
    int s = 0;
#pragma unroll
    for (int k = 0; k < 4; ++k) { int i = base + k; if (i < N) s += count[i]; }
    tsum[threadIdx.x] = s;
    __syncthreads();
    for (int off = 128; off > 0; off >>= 1) {
        if (threadIdx.x < off) tsum[threadIdx.x] += tsum[threadIdx.x + off];
        __syncthreads();
    }
    if (threadIdx.x == 0) bsum[blockIdx.x] = tsum[0];
}

// ---- Scan B: exclusive scan of block partials (tiny, serial) ----
__global__ void scan_b(int* __restrict__ bsum, int* __restrict__ rowptr, int nb, int N) {
    if (threadIdx.x == 0) {
        int run = 0;
        for (int i = 0; i < nb; ++i) { int c = bsum[i]; bsum[i] = run; run += c; }
        rowptr[N] = run;   // == E
    }
}

// ---- Scan C: full exclusive scan -> rowptr; dinv = rsqrt(deg+1) ----
__global__ void scan_c(const int* __restrict__ count, const int* __restrict__ bsum,
                       int* __restrict__ rowptr, float* __restrict__ dinv, int N) {
    __shared__ int tsum[256];
    int base = blockIdx.x * 1024 + threadIdx.x * 4;
    int v[4]; int s = 0;
#pragma unroll
    for (int k = 0; k < 4; ++k) { int i = base + k; v[k] = (i < N) ? count[i] : 0; s += v[k]; }
    tsum[threadIdx.x] = s;
    __syncthreads();
    for (int off = 1; off < 256; off <<= 1) {
        int add = (threadIdx.x >= (unsigned)off) ? tsum[threadIdx.x - off] : 0;
        __syncthreads();
        tsum[threadIdx.x] += add;
        __syncthreads();
    }
    int run = tsum[threadIdx.x] - s + bsum[blockIdx.x];   // exclusive thread offset
#pragma unroll
    for (int k = 0; k < 4; ++k) {
        int i = base + k;
        if (i < N) {
            rowptr[i] = run;
            dinv[i] = rsqrtf((float)(v[k] + 1));   // +1 self-loop
            run += v[k];
        }
    }
}

// ---- GEMM: y = (z @ W) * dinv[row] ----
__global__ void gemm_zw(const float* __restrict__ z, const float* __restrict__ W,
                        const float* __restrict__ dinv, float* __restrict__ y, int N) {
    __shared__ float Ws[IN_CH * OUT_CH];
    for (int i = threadIdx.x; i < IN_CH * OUT_CH; i += blockDim.x) Ws[i] = W[i];
    __syncthreads();

    const int rowsPerBlk = blockDim.x >> 6;
    const int col  = threadIdx.x & 63;
    const int warp = threadIdx.x >> 6;

    for (int row = blockIdx.x * rowsPerBlk + warp; row < N;
         row += gridDim.x * rowsPerBlk) {
        const float4* zr = (const float4*)(z + (size_t)row * IN_CH);
        float acc = 0.f;
#pragma unroll
        for (int k4 = 0; k4 < IN_CH / 4; ++k4) {
            float4 v = zr[k4];
            acc = fmaf(v.x, Ws[(k4 * 4 + 0) * OUT_CH + col], acc);
            acc = fmaf(v.y, Ws[(k4 * 4 + 1) * OUT_CH + col], acc);
            acc = fmaf(v.z, Ws[(k4 * 4 + 2) * OUT_CH + col], acc);
            acc = fmaf(v.w, Ws[(k4 * 4 + 3) * OUT_CH + col], acc);
        }
        y[(size_t)row * OUT_CH + col] = acc * dinv[row];
    }
}

// ---- Fill: CSR column array. atomicSub leaves count[] == 0 afterwards. ----
__global__ void fill_csr(const int* __restrict__ ei, const int* __restrict__ rowptr,
                         int* __restrict__ count, int* __restrict__ col, int E) {
    int e = blockIdx.x * blockDim.x + threadIdx.x;
    if (e >= E) return;
    int src = ei[e];
    int dst = ei[E + e];
    int slot = atomicSub(&count[dst], 1) - 1;    // count..1 -> slot count-1..0
    col[rowptr[dst] + slot] = src;
}

// ---- Gather: one wave per dst node; register accumulate; fused epilogue ----
__global__ void gather_nodes(const int* __restrict__ rowptr, const int* __restrict__ col,
                             const float* __restrict__ y, const float* __restrict__ dinv,
                             const float* __restrict__ b, float* __restrict__ out, int N) {
    int d = blockIdx.x * (blockDim.x >> 6) + (threadIdx.x >> 6);
    if (d >= N) return;
    int lane = threadIdx.x & 63;
    int beg = rowptr[d], end = rowptr[d + 1];
    float acc = y[(size_t)d * OUT_CH + lane];    // self-loop: x[d]*dinv[d] (·dinv[d] below)
    int j = beg;
    for (; j + 3 < end; j += 4) {
        int s0 = col[j], s1 = col[j + 1], s2 = col[j + 2], s3 = col[j + 3];
        float v0 = y[(size_t)s0 * OUT_CH + lane];
        float v1 = y[(size_t)s1 * OUT_CH + lane];
        float v2 = y[(size_t)s2 * OUT_CH + lane];
        float v3 = y[(size_t)s3 * OUT_CH + lane];
        acc += v0; acc += v1; acc += v2; acc += v3;
    }
    for (; j < end; ++j) acc += y[(size_t)col[j] * OUT_CH + lane];
    out[(size_t)d * OUT_CH + lane] = fmaxf(fmaf(acc, dinv[d], b[lane]), 0.f);
}

extern "C" void kernel_launch(void* const* d_in, const int* in_sizes, int n_in,
                              void* d_out, int out_size, void* d_ws, size_t ws_size,
                              hipStream_t stream) {
    const float* z  = (const float*)d_in[0];
    const int*   ei = (const int*)d_in[1];     // int32 [2, E]
    const float* W  = (const float*)d_in[2];
    const float* b  = (const float*)d_in[3];
    float*       out = (float*)d_out;

    const int N = in_sizes[0] / IN_CH;   // 50000
    const int E = in_sizes[1] / 2;       // 800000
    const int NB = (N + 1023) / 1024;    // scan blocks (49)

    // ws layout: y [N*64 f] | col [E i] | count [N i] | rowptr [N+1 i] | dinv [N f] | bsum [NB i]
    float* y      = (float*)d_ws;
    int*   col    = (int*)(y + (size_t)N * OUT_CH);
    int*   count  = col + E;
    int*   rowptr = count + N;
    float* dinv   = (float*)(rowptr + N + 1);
    int*   bsum   = (int*)(dinv + N);

    hipMemsetAsync(count, 0, (size_t)N * sizeof(int), stream);

    // degree histogram on dst
    hist_dst<<<(E + 255) / 256, 256, 0, stream>>>(ei + E, count, E);

    // exclusive prefix scan -> rowptr; dinv
    scan_a<<<NB, 256, 0, stream>>>(count, bsum, N);
    scan_b<<<1, 64, 0, stream>>>(bsum, rowptr, NB, N);
    scan_c<<<NB, 256, 0, stream>>>(count, bsum, rowptr, dinv, N);

    // y = (z @ W) * dinv
    gemm_zw<<<512, 256, 0, stream>>>(z, W, dinv, y, N);

    // CSR fill (consumes count back to zero)
    fill_csr<<<(E + 255) / 256, 256, 0, stream>>>(ei, rowptr, count, col, E);

    // gather + epilogue
    gather_nodes<<<(N * 64 + 255) / 256, 256, 0, stream>>>(rowptr, col, y, dinv, b, out, N);
}

// Round 4
// 201.266 us; speedup vs baseline: 1.8495x; 1.3322x over previous
//
#include <hip/hip_runtime.h>

#define IN_CH 128
#define OUT_CH 64
#define ROWS_PER_WAVE 8

// ---- Kernel: histogram of dst (int32 atomics) ----
__global__ void hist_dst(const int* __restrict__ dst, int* __restrict__ count, int E) {
    int i = blockIdx.x * blockDim.x + threadIdx.x;
    if (i < E) atomicAdd(&count[dst[i]], 1);
}

// ---- Scan A: per-1024-chunk partial sums ----
__global__ void scan_a(const int* __restrict__ count, int* __restrict__ bsum, int N) {
    __shared__ int tsum[256];
    int base = blockIdx.x * 1024 + threadIdx.x * 4;
    int s = 0;
#pragma unroll
    for (int k = 0; k < 4; ++k) { int i = base + k; if (i < N) s += count[i]; }
    tsum[threadIdx.x] = s;
    __syncthreads();
    for (int off = 128; off > 0; off >>= 1) {
        if (threadIdx.x < off) tsum[threadIdx.x] += tsum[threadIdx.x + off];
        __syncthreads();
    }
    if (threadIdx.x == 0) bsum[blockIdx.x] = tsum[0];
}

// ---- Scan B: exclusive scan of block partials (tiny, serial) ----
__global__ void scan_b(int* __restrict__ bsum, int* __restrict__ rowptr, int nb, int N) {
    if (threadIdx.x == 0) {
        int run = 0;
        for (int i = 0; i < nb; ++i) { int c = bsum[i]; bsum[i] = run; run += c; }
        rowptr[N] = run;   // == E
    }
}

// ---- Scan C: full exclusive scan -> rowptr; dinv = rsqrt(deg+1) ----
__global__ void scan_c(const int* __restrict__ count, const int* __restrict__ bsum,
                       int* __restrict__ rowptr, float* __restrict__ dinv, int N) {
    __shared__ int tsum[256];
    int base = blockIdx.x * 1024 + threadIdx.x * 4;
    int v[4]; int s = 0;
#pragma unroll
    for (int k = 0; k < 4; ++k) { int i = base + k; v[k] = (i < N) ? count[i] : 0; s += v[k]; }
    tsum[threadIdx.x] = s;
    __syncthreads();
    for (int off = 1; off < 256; off <<= 1) {
        int add = (threadIdx.x >= (unsigned)off) ? tsum[threadIdx.x - off] : 0;
        __syncthreads();
        tsum[threadIdx.x] += add;
        __syncthreads();
    }
    int run = tsum[threadIdx.x] - s + bsum[blockIdx.x];   // exclusive thread offset
#pragma unroll
    for (int k = 0; k < 4; ++k) {
        int i = base + k;
        if (i < N) {
            rowptr[i] = run;
            dinv[i] = rsqrtf((float)(v[k] + 1));   // +1 self-loop
            run += v[k];
        }
    }
}

// ---- GEMM: y = (z @ W) * dinv[row].  Wave computes 8 rows x 64 cols. ----
// Per k: 1 LDS read (Ws[k][col]) amortized over 8 FMAs; 8 independent acc
// chains give ILP; z read as broadcast float4 (wave-uniform address -> L1).
__global__ void gemm_zw(const float* __restrict__ z, const float* __restrict__ W,
                        const float* __restrict__ dinv, float* __restrict__ y, int N) {
    __shared__ float Ws[IN_CH * OUT_CH];
    for (int i = threadIdx.x; i < IN_CH * OUT_CH; i += blockDim.x) Ws[i] = W[i];
    __syncthreads();

    const int wavesPerBlk = blockDim.x >> 6;
    const int col  = threadIdx.x & 63;
    const int warp = threadIdx.x >> 6;
    const int nGroups = (N + ROWS_PER_WAVE - 1) / ROWS_PER_WAVE;

    for (int g = blockIdx.x * wavesPerBlk + warp; g < nGroups;
         g += gridDim.x * wavesPerBlk) {
        const int row0 = g * ROWS_PER_WAVE;
        const int nr = min(ROWS_PER_WAVE, N - row0);
        const float* zb = z + (size_t)row0 * IN_CH;

        float acc[ROWS_PER_WAVE];
#pragma unroll
        for (int r = 0; r < ROWS_PER_WAVE; ++r) acc[r] = 0.f;

        if (nr == ROWS_PER_WAVE) {
#pragma unroll
            for (int k4 = 0; k4 < IN_CH / 4; ++k4) {
                float4 zv[ROWS_PER_WAVE];
#pragma unroll
                for (int r = 0; r < ROWS_PER_WAVE; ++r)
                    zv[r] = *(const float4*)(zb + (size_t)r * IN_CH + k4 * 4);
#pragma unroll
                for (int j = 0; j < 4; ++j) {
                    float w = Ws[(k4 * 4 + j) * OUT_CH + col];
#pragma unroll
                    for (int r = 0; r < ROWS_PER_WAVE; ++r)
                        acc[r] = fmaf(((const float*)&zv[r])[j], w, acc[r]);
                }
            }
#pragma unroll
            for (int r = 0; r < ROWS_PER_WAVE; ++r)
                y[(size_t)(row0 + r) * OUT_CH + col] = acc[r] * dinv[row0 + r];
        } else {
            for (int r = 0; r < nr; ++r) {
                float a = 0.f;
                for (int k = 0; k < IN_CH; ++k)
                    a = fmaf(zb[(size_t)r * IN_CH + k], Ws[k * OUT_CH + col], a);
                y[(size_t)(row0 + r) * OUT_CH + col] = a * dinv[row0 + r];
            }
        }
    }
}

// ---- Fill: CSR column array. atomicSub leaves count[] == 0 afterwards. ----
__global__ void fill_csr(const int* __restrict__ ei, const int* __restrict__ rowptr,
                         int* __restrict__ count, int* __restrict__ col, int E) {
    int e = blockIdx.x * blockDim.x + threadIdx.x;
    if (e >= E) return;
    int src = ei[e];
    int dst = ei[E + e];
    int slot = atomicSub(&count[dst], 1) - 1;    // count..1 -> slot count-1..0
    col[rowptr[dst] + slot] = src;
}

// ---- Gather: one wave per dst node; register accumulate; fused epilogue ----
__global__ void gather_nodes(const int* __restrict__ rowptr, const int* __restrict__ col,
                             const float* __restrict__ y, const float* __restrict__ dinv,
                             const float* __restrict__ b, float* __restrict__ out, int N) {
    int d = blockIdx.x * (blockDim.x >> 6) + (threadIdx.x >> 6);
    if (d >= N) return;
    int lane = threadIdx.x & 63;
    int beg = rowptr[d], end = rowptr[d + 1];
    float acc = y[(size_t)d * OUT_CH + lane];    // self-loop: x[d]*dinv[d] (·dinv[d] below)
    int j = beg;
    for (; j + 3 < end; j += 4) {
        int s0 = col[j], s1 = col[j + 1], s2 = col[j + 2], s3 = col[j + 3];
        float v0 = y[(size_t)s0 * OUT_CH + lane];
        float v1 = y[(size_t)s1 * OUT_CH + lane];
        float v2 = y[(size_t)s2 * OUT_CH + lane];
        float v3 = y[(size_t)s3 * OUT_CH + lane];
        acc += v0; acc += v1; acc += v2; acc += v3;
    }
    for (; j < end; ++j) acc += y[(size_t)col[j] * OUT_CH + lane];
    out[(size_t)d * OUT_CH + lane] = fmaxf(fmaf(acc, dinv[d], b[lane]), 0.f);
}

extern "C" void kernel_launch(void* const* d_in, const int* in_sizes, int n_in,
                              void* d_out, int out_size, void* d_ws, size_t ws_size,
                              hipStream_t stream) {
    const float* z  = (const float*)d_in[0];
    const int*   ei = (const int*)d_in[1];     // int32 [2, E]
    const float* W  = (const float*)d_in[2];
    const float* b  = (const float*)d_in[3];
    float*       out = (float*)d_out;

    const int N = in_sizes[0] / IN_CH;   // 50000
    const int E = in_sizes[1] / 2;       // 800000
    const int NB = (N + 1023) / 1024;    // scan blocks (49)

    // ws layout: y [N*64 f] | col [E i] | count [N i] | rowptr [N+1 i] | dinv [N f] | bsum [NB i]
    float* y      = (float*)d_ws;
    int*   col    = (int*)(y + (size_t)N * OUT_CH);
    int*   count  = col + E;
    int*   rowptr = count + N;
    float* dinv   = (float*)(rowptr + N + 1);
    int*   bsum   = (int*)(dinv + N);

    hipMemsetAsync(count, 0, (size_t)N * sizeof(int), stream);

    // degree histogram on dst
    hist_dst<<<(E + 255) / 256, 256, 0, stream>>>(ei + E, count, E);

    // exclusive prefix scan -> rowptr; dinv
    scan_a<<<NB, 256, 0, stream>>>(count, bsum, N);
    scan_b<<<1, 64, 0, stream>>>(bsum, rowptr, NB, N);
    scan_c<<<NB, 256, 0, stream>>>(count, bsum, rowptr, dinv, N);

    // y = (z @ W) * dinv  (wave computes 8 rows)
    {
        int nGroups = (N + ROWS_PER_WAVE - 1) / ROWS_PER_WAVE;   // 6250
        int blocks = (nGroups + 3) / 4;                          // 4 waves/block
        gemm_zw<<<blocks, 256, 0, stream>>>(z, W, dinv, y, N);
    }

    // CSR fill (consumes count back to zero)
    fill_csr<<<(E + 255) / 256, 256, 0, stream>>>(ei, rowptr, count, col, E);

    // gather + epilogue
    gather_nodes<<<(N * 64 + 255) / 256, 256, 0, stream>>>(rowptr, col, y, dinv, b, out, N);
}

// Round 5
// 163.556 us; speedup vs baseline: 2.2760x; 1.2306x over previous
//
#include <hip/hip_runtime.h>

#define IN_CH 128
#define OUT_CH 64
#define TILE_ROWS 32
#define ROWS_PER_WAVE 8

// ---- Kernel: histogram of dst (int32 atomics) ----
__global__ void hist_dst(const int* __restrict__ dst, int* __restrict__ count, int E) {
    int i = blockIdx.x * blockDim.x + threadIdx.x;
    if (i < E) atomicAdd(&count[dst[i]], 1);
}

// ---- Scan A: per-1024-chunk partial sums ----
__global__ void scan_a(const int* __restrict__ count, int* __restrict__ bsum, int N) {
    __shared__ int tsum[256];
    int base = blockIdx.x * 1024 + threadIdx.x * 4;
    int s = 0;
#pragma unroll
    for (int k = 0; k < 4; ++k) { int i = base + k; if (i < N) s += count[i]; }
    tsum[threadIdx.x] = s;
    __syncthreads();
    for (int off = 128; off > 0; off >>= 1) {
        if (threadIdx.x < off) tsum[threadIdx.x] += tsum[threadIdx.x + off];
        __syncthreads();
    }
    if (threadIdx.x == 0) bsum[blockIdx.x] = tsum[0];
}

// ---- Scan B: exclusive scan of block partials (tiny, serial) ----
__global__ void scan_b(int* __restrict__ bsum, int* __restrict__ rowptr, int nb, int N) {
    if (threadIdx.x == 0) {
        int run = 0;
        for (int i = 0; i < nb; ++i) { int c = bsum[i]; bsum[i] = run; run += c; }
        rowptr[N] = run;   // == E
    }
}

// ---- Scan C: full exclusive scan -> rowptr; dinv = rsqrt(deg+1) ----
__global__ void scan_c(const int* __restrict__ count, const int* __restrict__ bsum,
                       int* __restrict__ rowptr, float* __restrict__ dinv, int N) {
    __shared__ int tsum[256];
    int base = blockIdx.x * 1024 + threadIdx.x * 4;
    int v[4]; int s = 0;
#pragma unroll
    for (int k = 0; k < 4; ++k) { int i = base + k; v[k] = (i < N) ? count[i] : 0; s += v[k]; }
    tsum[threadIdx.x] = s;
    __syncthreads();
    for (int off = 1; off < 256; off <<= 1) {
        int add = (threadIdx.x >= (unsigned)off) ? tsum[threadIdx.x - off] : 0;
        __syncthreads();
        tsum[threadIdx.x] += add;
        __syncthreads();
    }
    int run = tsum[threadIdx.x] - s + bsum[blockIdx.x];   // exclusive thread offset
#pragma unroll
    for (int k = 0; k < 4; ++k) {
        int i = base + k;
        if (i < N) {
            rowptr[i] = run;
            dinv[i] = rsqrtf((float)(v[k] + 1));   // +1 self-loop
            run += v[k];
        }
    }
}

// ---- GEMM: y = (z @ W) * dinv[row] ----
// Block stages a 32-row z tile into LDS with per-lane coalesced float4 loads
// (1 KB/instr), then each of 4 waves computes 8 rows x 64 cols reading z back
// as broadcast ds_read_b128 and W as lane-consecutive ds_read_b32.
__global__ void gemm_zw(const float* __restrict__ z, const float* __restrict__ W,
                        const float* __restrict__ dinv, float* __restrict__ y, int N) {
    __shared__ float Ws[IN_CH * OUT_CH];      // 32 KB
    __shared__ float Zs[TILE_ROWS * IN_CH];   // 16 KB

    // stage W once per block (coalesced float4)
    {
        const float4* W4 = (const float4*)W;
        float4* Ws4 = (float4*)Ws;
        for (int i = threadIdx.x; i < IN_CH * OUT_CH / 4; i += blockDim.x)
            Ws4[i] = W4[i];
    }

    const int col  = threadIdx.x & 63;
    const int warp = threadIdx.x >> 6;
    const int nTiles = (N + TILE_ROWS - 1) / TILE_ROWS;

    for (int t = blockIdx.x; t < nTiles; t += gridDim.x) {
        const int row0 = t * TILE_ROWS;
        const int nr = min(TILE_ROWS, N - row0);

        __syncthreads();   // Zs safe to overwrite (also orders W-stage on iter 0)
        {
            const float4* zt = (const float4*)(z + (size_t)row0 * IN_CH);
            float4* Zs4 = (float4*)Zs;
            const int n4 = nr * (IN_CH / 4);
            for (int i = threadIdx.x; i < n4; i += blockDim.x)
                Zs4[i] = zt[i];   // per-lane coalesced: 64 lanes x 16 B = 1 KB/instr
        }
        __syncthreads();

        const int rbase = warp * ROWS_PER_WAVE;
        if (rbase >= nr) continue;
        const int nrw = min(ROWS_PER_WAVE, nr - rbase);

        if (nrw == ROWS_PER_WAVE) {
            float acc[ROWS_PER_WAVE];
#pragma unroll
            for (int r = 0; r < ROWS_PER_WAVE; ++r) acc[r] = 0.f;

#pragma unroll
            for (int k4 = 0; k4 < IN_CH / 4; ++k4) {
                float4 zv[ROWS_PER_WAVE];
#pragma unroll
                for (int r = 0; r < ROWS_PER_WAVE; ++r)
                    zv[r] = *(const float4*)&Zs[(rbase + r) * IN_CH + k4 * 4];  // broadcast b128
#pragma unroll
                for (int j = 0; j < 4; ++j) {
                    float w = Ws[(k4 * 4 + j) * OUT_CH + col];                 // conflict-free b32
#pragma unroll
                    for (int r = 0; r < ROWS_PER_WAVE; ++r)
                        acc[r] = fmaf(((const float*)&zv[r])[j], w, acc[r]);
                }
            }
#pragma unroll
            for (int r = 0; r < ROWS_PER_WAVE; ++r) {
                int row = row0 + rbase + r;
                y[(size_t)row * OUT_CH + col] = acc[r] * dinv[row];
            }
        } else {
            for (int r = 0; r < nrw; ++r) {
                int row = row0 + rbase + r;
                float a = 0.f;
                for (int k = 0; k < IN_CH; ++k)
                    a = fmaf(Zs[(rbase + r) * IN_CH + k], Ws[k * OUT_CH + col], a);
                y[(size_t)row * OUT_CH + col] = a * dinv[row];
            }
        }
    }
}

// ---- Fill: CSR column array. atomicSub leaves count[] == 0 afterwards. ----
__global__ void fill_csr(const int* __restrict__ ei, const int* __restrict__ rowptr,
                         int* __restrict__ count, int* __restrict__ col, int E) {
    int e = blockIdx.x * blockDim.x + threadIdx.x;
    if (e >= E) return;
    int src = ei[e];
    int dst = ei[E + e];
    int slot = atomicSub(&count[dst], 1) - 1;    // count..1 -> slot count-1..0
    col[rowptr[dst] + slot] = src;
}

// ---- Gather: one wave per dst node; register accumulate; fused epilogue ----
__global__ void gather_nodes(const int* __restrict__ rowptr, const int* __restrict__ col,
                             const float* __restrict__ y, const float* __restrict__ dinv,
                             const float* __restrict__ b, float* __restrict__ out, int N) {
    int d = blockIdx.x * (blockDim.x >> 6) + (threadIdx.x >> 6);
    if (d >= N) return;
    int lane = threadIdx.x & 63;
    int beg = rowptr[d], end = rowptr[d + 1];
    float acc = y[(size_t)d * OUT_CH + lane];    // self-loop term
    int j = beg;
    for (; j + 3 < end; j += 4) {
        int s0 = col[j], s1 = col[j + 1], s2 = col[j + 2], s3 = col[j + 3];
        float v0 = y[(size_t)s0 * OUT_CH + lane];
        float v1 = y[(size_t)s1 * OUT_CH + lane];
        float v2 = y[(size_t)s2 * OUT_CH + lane];
        float v3 = y[(size_t)s3 * OUT_CH + lane];
        acc += v0; acc += v1; acc += v2; acc += v3;
    }
    for (; j < end; ++j) acc += y[(size_t)col[j] * OUT_CH + lane];
    out[(size_t)d * OUT_CH + lane] = fmaxf(fmaf(acc, dinv[d], b[lane]), 0.f);
}

extern "C" void kernel_launch(void* const* d_in, const int* in_sizes, int n_in,
                              void* d_out, int out_size, void* d_ws, size_t ws_size,
                              hipStream_t stream) {
    const float* z  = (const float*)d_in[0];
    const int*   ei = (const int*)d_in[1];     // int32 [2, E]
    const float* W  = (const float*)d_in[2];
    const float* b  = (const float*)d_in[3];
    float*       out = (float*)d_out;

    const int N = in_sizes[0] / IN_CH;   // 50000
    const int E = in_sizes[1] / 2;       // 800000
    const int NB = (N + 1023) / 1024;    // scan blocks (49)

    // ws layout: y [N*64 f] | col [E i] | count [N i] | rowptr [N+1 i] | dinv [N f] | bsum [NB i]
    float* y      = (float*)d_ws;
    int*   col    = (int*)(y + (size_t)N * OUT_CH);
    int*   count  = col + E;
    int*   rowptr = count + N;
    float* dinv   = (float*)(rowptr + N + 1);
    int*   bsum   = (int*)(dinv + N);

    hipMemsetAsync(count, 0, (size_t)N * sizeof(int), stream);

    // degree histogram on dst
    hist_dst<<<(E + 255) / 256, 256, 0, stream>>>(ei + E, count, E);

    // exclusive prefix scan -> rowptr; dinv
    scan_a<<<NB, 256, 0, stream>>>(count, bsum, N);
    scan_b<<<1, 64, 0, stream>>>(bsum, rowptr, NB, N);
    scan_c<<<NB, 256, 0, stream>>>(count, bsum, rowptr, dinv, N);

    // y = (z @ W) * dinv   (LDS-staged z, 3 blocks/CU resident, grid-stride)
    gemm_zw<<<768, 256, 0, stream>>>(z, W, dinv, y, N);

    // CSR fill (consumes count back to zero)
    fill_csr<<<(E + 255) / 256, 256, 0, stream>>>(ei, rowptr, count, col, E);

    // gather + epilogue
    gather_nodes<<<(N * 64 + 255) / 256, 256, 0, stream>>>(rowptr, col, y, dinv, b, out, N);
}